// Round 1
// baseline (3402.633 us; speedup 1.0000x reference)
//
#include <hip/hip_runtime.h>
#include <math.h>

#define DMODEL 1024
#define NHEAD  16
#define DK     64
#define BB     2
#define LL     2048
#define MTOT   (BB*LL)   // 4096

// ---------------------------------------------------------------------------
// GEMM: C = A @ W + bias.  A: [M,1024] row-major, W: [1024,1024] row-major.
// mode 0/1: out -> qkv layout [b,h,l,dk]
// mode 2:   A scaled per-row by delta, out -> qkv layout
// mode 3:   out -> row-major [M, DMODEL]
// ---------------------------------------------------------------------------
__global__ __launch_bounds__(256) void gemm_k(
    const float* __restrict__ A, const float* __restrict__ delta,
    const float* __restrict__ W, const float* __restrict__ bias,
    float* __restrict__ out, int mode)
{
    __shared__ float As[16][64];   // [k][m]
    __shared__ float Bs[16][64];   // [k][n]
    const int tid = threadIdx.x;
    const int tx = tid & 15;
    const int ty = tid >> 4;
    const int bm = blockIdx.y * 64;
    const int bn = blockIdx.x * 64;

    float c[4][4] = {};

    const int ar  = tid >> 2;         // 0..63  (A row within tile)
    const int ac4 = (tid & 3) * 4;    // 0,4,8,12
    const int wr  = tid >> 4;         // 0..15  (W row within tile)
    const int wc4 = (tid & 15) * 4;   // 0..60

    float scale = 1.0f;
    if (mode == 2) scale = delta[bm + ar];

    for (int k0 = 0; k0 < DMODEL; k0 += 16) {
        float4 a4 = *(const float4*)(A + (size_t)(bm + ar) * DMODEL + k0 + ac4);
        As[ac4 + 0][ar] = a4.x * scale;
        As[ac4 + 1][ar] = a4.y * scale;
        As[ac4 + 2][ar] = a4.z * scale;
        As[ac4 + 3][ar] = a4.w * scale;
        float4 b4 = *(const float4*)(W + (size_t)(k0 + wr) * DMODEL + bn + wc4);
        *(float4*)(&Bs[wr][wc4]) = b4;
        __syncthreads();
#pragma unroll
        for (int kk = 0; kk < 16; ++kk) {
            float a[4], bb[4];
#pragma unroll
            for (int i = 0; i < 4; ++i) a[i] = As[kk][ty * 4 + i];
#pragma unroll
            for (int j = 0; j < 4; ++j) bb[j] = Bs[kk][tx * 4 + j];
#pragma unroll
            for (int i = 0; i < 4; ++i)
#pragma unroll
                for (int j = 0; j < 4; ++j)
                    c[i][j] += a[i] * bb[j];
        }
        __syncthreads();
    }

#pragma unroll
    for (int i = 0; i < 4; ++i) {
        const int m = bm + ty * 4 + i;
#pragma unroll
        for (int j = 0; j < 4; ++j) {
            const int n = bn + tx * 4 + j;
            float v = c[i][j] + bias[n];
            if (mode == 3) {
                out[(size_t)m * DMODEL + n] = v;
            } else {
                const int b = m >> 11, l = m & (LL - 1);
                const int h = n >> 6,  dd = n & 63;
                out[(((size_t)(b * NHEAD + h) * LL) + l) * DK + dd] = v;
            }
        }
    }
}

// ---------------------------------------------------------------------------
// Flash attention per (b,h,16 q rows): online softmax over 64-key tiles.
// Writes context [B,L,DMODEL] (d = h*64+dd) and per-(b,h,q) stats m,l.
// ---------------------------------------------------------------------------
__global__ __launch_bounds__(256) void attn_flash_k(
    const float* __restrict__ Q, const float* __restrict__ K,
    const float* __restrict__ V, const float* __restrict__ delta,
    float* __restrict__ ctx, float* __restrict__ mout, float* __restrict__ lout)
{
    __shared__ float Qs[16][65];
    __shared__ float Ks[64][65];
    __shared__ float Vs[64][65];
    __shared__ float Ps[16][64];
    __shared__ float logd[64];
    __shared__ float m_s[16], l_s[16];

    const int tid = threadIdx.x;
    const int bh  = blockIdx.y;          // b*NHEAD + h
    const int b   = bh >> 4;
    const int h   = bh & 15;
    const int q0  = blockIdx.x * 16;

    const size_t base = (size_t)bh * LL * DK;

    // stage Q tile: 16x64 floats = 256 float4, one per thread
    {
        const int r = tid >> 4, c4 = (tid & 15) * 4;
        float4 q4 = *(const float4*)(Q + base + (size_t)(q0 + r) * DK + c4);
        Qs[r][c4 + 0] = q4.x; Qs[r][c4 + 1] = q4.y;
        Qs[r][c4 + 2] = q4.z; Qs[r][c4 + 3] = q4.w;
    }
    if (tid < 16) { m_s[tid] = -1e30f; l_s[tid] = 0.0f; }

    const int qi = tid >> 4;    // 0..15 : q row
    const int jg = tid & 15;    // 0..15 : key group (score phase) / d group (ctx phase)
    float ctxacc[4] = {0.f, 0.f, 0.f, 0.f};

    for (int k0 = 0; k0 < LL; k0 += 64) {
        // stage K,V tiles (64x64 each = 1024 float4 -> 4 per thread)
#pragma unroll
        for (int cnk = 0; cnk < 4; ++cnk) {
            int f4 = cnk * 256 + tid;            // 0..1023
            int r = f4 >> 4, c4 = (f4 & 15) * 4;
            float4 kk4 = *(const float4*)(K + base + (size_t)(k0 + r) * DK + c4);
            Ks[r][c4+0]=kk4.x; Ks[r][c4+1]=kk4.y; Ks[r][c4+2]=kk4.z; Ks[r][c4+3]=kk4.w;
            float4 vv4 = *(const float4*)(V + base + (size_t)(k0 + r) * DK + c4);
            Vs[r][c4+0]=vv4.x; Vs[r][c4+1]=vv4.y; Vs[r][c4+2]=vv4.z; Vs[r][c4+3]=vv4.w;
        }
        if (tid < 64) logd[tid] = __logf(delta[b * LL + k0 + tid] + 1e-6f);
        __syncthreads();

        // scores: thread (qi,jg) computes keys j = jg*4 .. jg*4+3
        float s[4] = {0.f, 0.f, 0.f, 0.f};
#pragma unroll 16
        for (int d = 0; d < 64; ++d) {
            float qv = Qs[qi][d];
#pragma unroll
            for (int jj = 0; jj < 4; ++jj)
                s[jj] += qv * Ks[jg * 4 + jj][d];
        }
        const int qpos = q0 + qi;
#pragma unroll
        for (int jj = 0; jj < 4; ++jj) {
            int kpos = k0 + jg * 4 + jj;
            s[jj] = s[jj] * 0.125f - 0.1f * fabsf((float)(qpos - kpos)) + logd[jg * 4 + jj];
        }
        // tile row-max over the 16 lanes of this q-row group
        float tmax = fmaxf(fmaxf(s[0], s[1]), fmaxf(s[2], s[3]));
        for (int off = 8; off; off >>= 1)
            tmax = fmaxf(tmax, __shfl_xor(tmax, off, 16));
        float m_old = m_s[qi];
        float m_new = fmaxf(m_old, tmax);
        float p[4], psum = 0.f;
#pragma unroll
        for (int jj = 0; jj < 4; ++jj) { p[jj] = __expf(s[jj] - m_new); psum += p[jj]; }
        for (int off = 8; off; off >>= 1)
            psum += __shfl_xor(psum, off, 16);
        float alpha = __expf(m_old - m_new);   // uniform across the 16-lane group
        if (jg == 0) {
            m_s[qi] = m_new;
            l_s[qi] = l_s[qi] * alpha + psum;
        }
#pragma unroll
        for (int jj = 0; jj < 4; ++jj) Ps[qi][jg * 4 + jj] = p[jj];
        __syncthreads();

        // ctx update: thread (qi, dg=jg) owns d = dg*4..+3 of row qi
#pragma unroll
        for (int dd = 0; dd < 4; ++dd) ctxacc[dd] *= alpha;
#pragma unroll 8
        for (int j = 0; j < 64; ++j) {
            float pj = Ps[qi][j];
#pragma unroll
            for (int dd = 0; dd < 4; ++dd)
                ctxacc[dd] += pj * Vs[j][jg * 4 + dd];
        }
        __syncthreads();
    }

    // write context (normalized) and stats
    {
        float inv = 1.0f / l_s[qi];
        float4 o;
        o.x = ctxacc[0] * inv; o.y = ctxacc[1] * inv;
        o.z = ctxacc[2] * inv; o.w = ctxacc[3] * inv;
        *(float4*)(ctx + ((size_t)b * LL + (q0 + qi)) * DMODEL + h * DK + jg * 4) = o;
    }
    if (tid < 16) {
        mout[(size_t)bh * LL + q0 + tid] = m_s[tid];
        lout[(size_t)bh * LL + q0 + tid] = l_s[tid];
    }
}

// ---------------------------------------------------------------------------
// attn.mean(heads): per (b, 16 q rows, 64 k cols) block, loop over heads,
// recompute scores, normalize with stored (m,l), accumulate, store once.
// ---------------------------------------------------------------------------
__global__ __launch_bounds__(256) void attn_mean_k(
    const float* __restrict__ Q, const float* __restrict__ K,
    const float* __restrict__ delta, const float* __restrict__ mws,
    const float* __restrict__ lws, float* __restrict__ outmean)
{
    __shared__ float Qs[16][65];
    __shared__ float Ks[64][65];
    __shared__ float logd[64];
    __shared__ float mrow[16], lrow[16];

    const int tid = threadIdx.x;
    const int k0 = blockIdx.x * 64;
    const int q0 = blockIdx.y * 16;
    const int b  = blockIdx.z;

    if (tid < 64) logd[tid] = __logf(delta[b * LL + k0 + tid] + 1e-6f);

    const int qi = tid >> 4, jg = tid & 15;
    float acc[4] = {0.f, 0.f, 0.f, 0.f};

    for (int h = 0; h < NHEAD; ++h) {
        const size_t base = ((size_t)(b * NHEAD + h)) * LL * DK;
        __syncthreads();   // previous-iter readers done before restaging
        {
            const int r = tid >> 4, c4 = (tid & 15) * 4;
            float4 q4 = *(const float4*)(Q + base + (size_t)(q0 + r) * DK + c4);
            Qs[r][c4+0]=q4.x; Qs[r][c4+1]=q4.y; Qs[r][c4+2]=q4.z; Qs[r][c4+3]=q4.w;
        }
#pragma unroll
        for (int cnk = 0; cnk < 4; ++cnk) {
            int f4 = cnk * 256 + tid;
            int r = f4 >> 4, c4 = (f4 & 15) * 4;
            float4 k4 = *(const float4*)(K + base + (size_t)(k0 + r) * DK + c4);
            Ks[r][c4+0]=k4.x; Ks[r][c4+1]=k4.y; Ks[r][c4+2]=k4.z; Ks[r][c4+3]=k4.w;
        }
        if (tid < 16) {
            mrow[tid] = mws[(size_t)(b * NHEAD + h) * LL + q0 + tid];
            lrow[tid] = lws[(size_t)(b * NHEAD + h) * LL + q0 + tid];
        }
        __syncthreads();

        float s[4] = {0.f, 0.f, 0.f, 0.f};
#pragma unroll 16
        for (int d = 0; d < 64; ++d) {
            float qv = Qs[qi][d];
#pragma unroll
            for (int jj = 0; jj < 4; ++jj)
                s[jj] += qv * Ks[jg * 4 + jj][d];
        }
        const int qpos = q0 + qi;
        float mi = mrow[qi];
        float inv = 1.0f / lrow[qi];
#pragma unroll
        for (int jj = 0; jj < 4; ++jj) {
            int kpos = k0 + jg * 4 + jj;
            float sv = s[jj] * 0.125f - 0.1f * fabsf((float)(qpos - kpos)) + logd[jg * 4 + jj];
            acc[jj] += __expf(sv - mi) * inv;
        }
    }

    const float invH = 1.0f / (float)NHEAD;
    float4 o;
    o.x = acc[0] * invH; o.y = acc[1] * invH;
    o.z = acc[2] * invH; o.w = acc[3] * invH;
    *(float4*)(outmean + ((size_t)b * LL + (q0 + qi)) * LL + k0 + jg * 4) = o;
}

// ---------------------------------------------------------------------------
extern "C" void kernel_launch(void* const* d_in, const int* in_sizes, int n_in,
                              void* d_out, int out_size, void* d_ws, size_t ws_size,
                              hipStream_t stream) {
    const float* x  = (const float*)d_in[0];
    const float* dr = (const float*)d_in[1];
    const float* Wq = (const float*)d_in[2];
    const float* bq = (const float*)d_in[3];
    const float* Wk = (const float*)d_in[4];
    const float* bk = (const float*)d_in[5];
    const float* Wv = (const float*)d_in[6];
    const float* bv = (const float*)d_in[7];
    const float* Wo = (const float*)d_in[8];
    const float* bo = (const float*)d_in[9];
    float* out = (float*)d_out;
    float* ws  = (float*)d_ws;

    float* Qw = ws;                                   // [B,H,L,DK]
    float* Kw = ws + 1 * (size_t)MTOT * DMODEL;       // [B,H,L,DK]
    float* Vw = ws + 2 * (size_t)MTOT * DMODEL;       // [B,H,L,DK]
    float* Cw = ws + 3 * (size_t)MTOT * DMODEL;       // context [B,L,DMODEL]
    float* Mw = ws + 4 * (size_t)MTOT * DMODEL;       // softmax max  [B,H,L]
    float* Lw = Mw + (size_t)BB * NHEAD * LL;         // softmax sum  [B,H,L]

    dim3 gg(DMODEL / 64, MTOT / 64);
    gemm_k<<<gg, 256, 0, stream>>>(x, dr, Wq, bq, Qw, 0);
    gemm_k<<<gg, 256, 0, stream>>>(x, dr, Wk, bk, Kw, 1);
    gemm_k<<<gg, 256, 0, stream>>>(x, dr, Wv, bv, Vw, 2);

    dim3 ga(LL / 16, BB * NHEAD);
    attn_flash_k<<<ga, 256, 0, stream>>>(Qw, Kw, Vw, dr, Cw, Mw, Lw);

    dim3 gm(LL / 64, LL / 16, BB);
    attn_mean_k<<<gm, 256, 0, stream>>>(Qw, Kw, dr, Mw, Lw,
                                        out + (size_t)MTOT * DMODEL);

    gemm_k<<<gg, 256, 0, stream>>>(Cw, dr, Wo, bo, out, 3);
}

// Round 2
// 391.727 us; speedup vs baseline: 8.6862x; 8.6862x over previous
//
#include <hip/hip_runtime.h>
#include <math.h>

#define DMODEL 1024
#define NHEAD  16
#define DK     64
#define BB     2
#define LL     2048
#define MTOT   (BB*LL)   // 4096

typedef __bf16 bf16_t;
typedef __bf16 bf16x8 __attribute__((ext_vector_type(8)));
typedef float  f32x4  __attribute__((ext_vector_type(4)));

static __device__ __forceinline__ f32x4 mfma16(bf16x8 a, bf16x8 b, f32x4 c) {
    return __builtin_amdgcn_mfma_f32_16x16x32_bf16(a, b, c, 0, 0, 0);
}

// ---------------------------------------------------------------------------
// prep: x -> bf16, x*delta -> bf16
// ---------------------------------------------------------------------------
__global__ __launch_bounds__(256) void prep_x_k(
    const float* __restrict__ x, const float* __restrict__ dr,
    bf16_t* __restrict__ xb, bf16_t* __restrict__ xdb)
{
    size_t gid = (size_t)blockIdx.x * 256 + threadIdx.x;   // 524288 total
    size_t off = gid * 8;
    float s = dr[off >> 10];
    float4 a = *(const float4*)(x + off);
    float4 c = *(const float4*)(x + off + 4);
    float va[8] = {a.x, a.y, a.z, a.w, c.x, c.y, c.z, c.w};
    bf16x8 o1, o2;
#pragma unroll
    for (int j = 0; j < 8; ++j) {
        o1[j] = (bf16_t)va[j];
        o2[j] = (bf16_t)(va[j] * s);
    }
    *(bf16x8*)(xb + off) = o1;
    *(bf16x8*)(xdb + off) = o2;
}

// ---------------------------------------------------------------------------
// prep: W[k][n] f32 -> Wt[n][k] bf16  (transpose + convert)
// ---------------------------------------------------------------------------
__global__ __launch_bounds__(256) void prep_wt_k(
    const float* __restrict__ W, bf16_t* __restrict__ Wt)
{
    __shared__ __align__(16) float Ts[64][68];
    const int tid = threadIdx.x;
    const int k0 = blockIdx.x * 64, n0 = blockIdx.y * 64;
#pragma unroll
    for (int i = 0; i < 4; ++i) {
        int u = tid + 256 * i, r = u >> 4, c4 = (u & 15) * 4;
        *(float4*)&Ts[r][c4] = *(const float4*)(W + (size_t)(k0 + r) * DMODEL + n0 + c4);
    }
    __syncthreads();
#pragma unroll
    for (int i = 0; i < 2; ++i) {
        int u = tid + 256 * i, n = u >> 3, k8 = (u & 7) * 8;
        bf16x8 v;
#pragma unroll
        for (int j = 0; j < 8; ++j) v[j] = (bf16_t)Ts[k8 + j][n];
        *(bf16x8*)(Wt + (size_t)(n0 + n) * DMODEL + k0 + k8) = v;
    }
}

__global__ __launch_bounds__(256) void prep_logd_k(
    const float* __restrict__ dr, float* __restrict__ logd)
{
    int i = blockIdx.x * 256 + threadIdx.x;
    if (i < MTOT) logd[i] = logf(dr[i] + 1e-6f);
}

// ---------------------------------------------------------------------------
// bf16 MFMA GEMM: C = A(bf16 [M,1024]) @ Wt^T(bf16 Wt=[N,K]) + bias
// mode 0: outb -> [b,h,l,dk] bf16; mode 2: outf -> [M,1024] f32
// ---------------------------------------------------------------------------
__global__ __launch_bounds__(256) void gemm_bf16_k(
    const bf16_t* __restrict__ A, const bf16_t* __restrict__ Wt,
    const float* __restrict__ bias, float* __restrict__ outf,
    bf16_t* __restrict__ outb, int mode)
{
    __shared__ __align__(16) bf16_t As[64][72];
    __shared__ __align__(16) bf16_t Bs[64][72];
    const int tid = threadIdx.x;
    const int lane = tid & 63, w = tid >> 6;
    const int quad = lane >> 4, n16 = lane & 15;
    const int m0 = blockIdx.y * 64, n0 = blockIdx.x * 64;

    f32x4 acc[4] = {};

    for (int K0 = 0; K0 < DMODEL; K0 += 64) {
        __syncthreads();
#pragma unroll
        for (int i = 0; i < 2; ++i) {
            int u = tid + 256 * i, r = u >> 3, c8 = (u & 7) * 8;
            *(bf16x8*)&As[r][c8] = *(const bf16x8*)(A + (size_t)(m0 + r) * DMODEL + K0 + c8);
            *(bf16x8*)&Bs[r][c8] = *(const bf16x8*)(Wt + (size_t)(n0 + r) * DMODEL + K0 + c8);
        }
        __syncthreads();
#pragma unroll
        for (int kc = 0; kc < 2; ++kc) {
            bf16x8 a = *(const bf16x8*)&As[w * 16 + n16][kc * 32 + quad * 8];
#pragma unroll
            for (int nt = 0; nt < 4; ++nt) {
                bf16x8 bfr = *(const bf16x8*)&Bs[nt * 16 + n16][kc * 32 + quad * 8];
                acc[nt] = mfma16(a, bfr, acc[nt]);
            }
        }
    }
#pragma unroll
    for (int nt = 0; nt < 4; ++nt) {
#pragma unroll
        for (int r = 0; r < 4; ++r) {
            int m = m0 + w * 16 + quad * 4 + r;
            int n = n0 + nt * 16 + n16;
            float v = acc[nt][r] + bias[n];
            if (mode == 0) {
                int b = m >> 11, l = m & (LL - 1);
                int h = n >> 6, dd = n & 63;
                outb[(((size_t)(b * NHEAD + h) * LL) + l) * DK + dd] = (bf16_t)v;
            } else {
                outf[(size_t)m * DMODEL + n] = v;
            }
        }
    }
}

// ---------------------------------------------------------------------------
// V[b,h,l,dk] bf16 -> Vt[b,h,dk,l] bf16
// ---------------------------------------------------------------------------
__global__ __launch_bounds__(256) void vtrans_k(
    const bf16_t* __restrict__ V, bf16_t* __restrict__ Vt)
{
    __shared__ __align__(16) bf16_t Ts[64][72];
    const int tid = threadIdx.x;
    const int bh = blockIdx.y;
    const int l0 = blockIdx.x * 64;
    const size_t base = (size_t)bh * LL * DK;
#pragma unroll
    for (int i = 0; i < 2; ++i) {
        int u = tid + 256 * i, r = u >> 3, c8 = (u & 7) * 8;
        *(bf16x8*)&Ts[r][c8] = *(const bf16x8*)(V + base + (size_t)(l0 + r) * DK + c8);
    }
    __syncthreads();
#pragma unroll
    for (int i = 0; i < 2; ++i) {
        int u = tid + 256 * i, dd = u >> 3, l8 = (u & 7) * 8;
        bf16x8 v;
#pragma unroll
        for (int j = 0; j < 8; ++j) v[j] = Ts[l8 + j][dd];
        *(bf16x8*)(Vt + base + (size_t)dd * LL + l0 + l8) = v;
    }
}

// ---------------------------------------------------------------------------
// MFMA flash attention: per block (b,h, 64 q rows); 4 waves x 16 q rows.
// Writes ctx bf16 [B,L,DMODEL] and per-(b,h,q) stats m,l.
// ---------------------------------------------------------------------------
__global__ __launch_bounds__(256) void attn_flash_mfma_k(
    const bf16_t* __restrict__ Q, const bf16_t* __restrict__ K,
    const bf16_t* __restrict__ Vt, const float* __restrict__ logd_g,
    bf16_t* __restrict__ ctx, float* __restrict__ mout, float* __restrict__ lout)
{
    __shared__ __align__(16) bf16_t Qs[64][72];
    __shared__ __align__(16) bf16_t Ks[64][72];
    __shared__ __align__(16) bf16_t Vts[64][72];   // [d][key]
    __shared__ __align__(16) bf16_t Ps[4][16][72]; // per-wave P buffer
    __shared__ float logds[64];

    const int tid = threadIdx.x;
    const int lane = tid & 63, w = tid >> 6;
    const int quad = lane >> 4, n16 = lane & 15;
    const int bh = blockIdx.y, b = bh >> 4, h = bh & 15;
    const int q0 = blockIdx.x * 64;
    const size_t base = (size_t)bh * LL * DK;

    // stage Q tile once
#pragma unroll
    for (int i = 0; i < 2; ++i) {
        int u = tid + 256 * i, r = u >> 3, c8 = (u & 7) * 8;
        *(bf16x8*)&Qs[r][c8] = *(const bf16x8*)(Q + base + (size_t)(q0 + r) * DK + c8);
    }
    __syncthreads();
    bf16x8 qa[2];
#pragma unroll
    for (int kc = 0; kc < 2; ++kc)
        qa[kc] = *(const bf16x8*)&Qs[w * 16 + n16][kc * 32 + quad * 8];

    float m_r[4], l_r[4];
    f32x4 o[4] = {};
#pragma unroll
    for (int r = 0; r < 4; ++r) { m_r[r] = -1e30f; l_r[r] = 0.f; }

    const int qrow = q0 + w * 16 + quad * 4;   // + r

    for (int k0 = 0; k0 < LL; k0 += 64) {
        __syncthreads();
#pragma unroll
        for (int i = 0; i < 2; ++i) {
            int u = tid + 256 * i, r = u >> 3, c8 = (u & 7) * 8;
            *(bf16x8*)&Ks[r][c8]  = *(const bf16x8*)(K + base + (size_t)(k0 + r) * DK + c8);
            *(bf16x8*)&Vts[r][c8] = *(const bf16x8*)(Vt + base + (size_t)r * LL + k0 + c8);
        }
        if (tid < 64) logds[tid] = logd_g[b * LL + k0 + tid];
        __syncthreads();

        // S = Q K^T
        f32x4 s[4] = {};
#pragma unroll
        for (int kc = 0; kc < 2; ++kc) {
#pragma unroll
            for (int nt = 0; nt < 4; ++nt) {
                bf16x8 kb = *(const bf16x8*)&Ks[nt * 16 + n16][kc * 32 + quad * 8];
                s[nt] = mfma16(qa[kc], kb, s[nt]);
            }
        }
        // bias
        float sv[4][4];
#pragma unroll
        for (int nt = 0; nt < 4; ++nt) {
            int kpos = k0 + nt * 16 + n16;
            float ld = logds[nt * 16 + n16];
#pragma unroll
            for (int r = 0; r < 4; ++r) {
                float d = (float)(qrow + r - kpos);
                sv[nt][r] = s[nt][r] * 0.125f - 0.1f * fabsf(d) + ld;
            }
        }
        // online softmax per row
#pragma unroll
        for (int r = 0; r < 4; ++r) {
            float rm = fmaxf(fmaxf(sv[0][r], sv[1][r]), fmaxf(sv[2][r], sv[3][r]));
#pragma unroll
            for (int off = 8; off >= 1; off >>= 1)
                rm = fmaxf(rm, __shfl_xor(rm, off));
            float mn = fmaxf(m_r[r], rm);
            float alpha = __expf(m_r[r] - mn);
            float psum = 0.f;
#pragma unroll
            for (int nt = 0; nt < 4; ++nt) {
                float p = __expf(sv[nt][r] - mn);
                sv[nt][r] = p;
                psum += p;
            }
#pragma unroll
            for (int off = 8; off >= 1; off >>= 1)
                psum += __shfl_xor(psum, off);
            l_r[r] = l_r[r] * alpha + psum;
            m_r[r] = mn;
#pragma unroll
            for (int dt = 0; dt < 4; ++dt) o[dt][r] *= alpha;
        }
        // P -> LDS (C-layout -> A-layout round trip, wave-private buffer)
#pragma unroll
        for (int nt = 0; nt < 4; ++nt)
#pragma unroll
            for (int r = 0; r < 4; ++r)
                Ps[w][quad * 4 + r][nt * 16 + n16] = (bf16_t)sv[nt][r];
        __threadfence_block();   // order P writes before A-frag reads (same wave)
        // O += P V
#pragma unroll
        for (int kc = 0; kc < 2; ++kc) {
            bf16x8 pa = *(const bf16x8*)&Ps[w][n16][kc * 32 + quad * 8];
#pragma unroll
            for (int dt = 0; dt < 4; ++dt) {
                bf16x8 vb = *(const bf16x8*)&Vts[dt * 16 + n16][kc * 32 + quad * 8];
                o[dt] = mfma16(pa, vb, o[dt]);
            }
        }
    }
    // epilogue
#pragma unroll
    for (int r = 0; r < 4; ++r) {
        float inv = 1.f / l_r[r];
        int q = qrow + r;
#pragma unroll
        for (int dt = 0; dt < 4; ++dt)
            ctx[((size_t)(b * LL) + q) * DMODEL + h * DK + dt * 16 + n16] =
                (bf16_t)(o[dt][r] * inv);
    }
    if (n16 == 0) {
#pragma unroll
        for (int r = 0; r < 4; ++r) {
            mout[(size_t)bh * LL + qrow + r] = m_r[r];
            lout[(size_t)bh * LL + qrow + r] = l_r[r];
        }
    }
}

// ---------------------------------------------------------------------------
// attn.mean(heads): per block (b, 64 q rows, 64 k cols); loop heads,
// recompute S with the bitwise-identical MFMA sequence, normalize via (m,l).
// ---------------------------------------------------------------------------
__global__ __launch_bounds__(256) void attn_mean_mfma_k(
    const bf16_t* __restrict__ Q, const bf16_t* __restrict__ K,
    const float* __restrict__ logd_g, const float* __restrict__ mws,
    const float* __restrict__ lws, float* __restrict__ outmean)
{
    __shared__ __align__(16) bf16_t Qs[64][72];
    __shared__ __align__(16) bf16_t Ks[64][72];
    __shared__ float logds[64], mrow[64], lrow[64];

    const int tid = threadIdx.x;
    const int lane = tid & 63, w = tid >> 6;
    const int quad = lane >> 4, n16 = lane & 15;
    const int k0 = blockIdx.x * 64, q0 = blockIdx.y * 64, b = blockIdx.z;

    if (tid < 64) logds[tid] = logd_g[b * LL + k0 + tid];

    const int qrow = q0 + w * 16 + quad * 4;
    f32x4 acc[4] = {};

    for (int h = 0; h < NHEAD; ++h) {
        __syncthreads();
        const size_t base = (size_t)(b * NHEAD + h) * LL * DK;
#pragma unroll
        for (int i = 0; i < 2; ++i) {
            int u = tid + 256 * i, r = u >> 3, c8 = (u & 7) * 8;
            *(bf16x8*)&Qs[r][c8] = *(const bf16x8*)(Q + base + (size_t)(q0 + r) * DK + c8);
            *(bf16x8*)&Ks[r][c8] = *(const bf16x8*)(K + base + (size_t)(k0 + r) * DK + c8);
        }
        if (tid < 64) {
            mrow[tid] = mws[(size_t)(b * NHEAD + h) * LL + q0 + tid];
            lrow[tid] = lws[(size_t)(b * NHEAD + h) * LL + q0 + tid];
        }
        __syncthreads();

        f32x4 s[4] = {};
#pragma unroll
        for (int kc = 0; kc < 2; ++kc) {
            bf16x8 qa = *(const bf16x8*)&Qs[w * 16 + n16][kc * 32 + quad * 8];
#pragma unroll
            for (int nt = 0; nt < 4; ++nt) {
                bf16x8 kb = *(const bf16x8*)&Ks[nt * 16 + n16][kc * 32 + quad * 8];
                s[nt] = mfma16(qa, kb, s[nt]);
            }
        }
#pragma unroll
        for (int r = 0; r < 4; ++r) {
            int row = w * 16 + quad * 4 + r;
            float mi = mrow[row];
            float inv = 1.f / lrow[row];
#pragma unroll
            for (int nt = 0; nt < 4; ++nt) {
                int kpos = k0 + nt * 16 + n16;
                float d = (float)(qrow + r - kpos);
                float svv = s[nt][r] * 0.125f - 0.1f * fabsf(d) + logds[nt * 16 + n16];
                acc[nt][r] += __expf(svv - mi) * inv;
            }
        }
    }
    const float invH = 1.f / (float)NHEAD;
#pragma unroll
    for (int nt = 0; nt < 4; ++nt)
#pragma unroll
        for (int r = 0; r < 4; ++r)
            outmean[((size_t)b * LL + qrow + r) * LL + k0 + nt * 16 + n16] =
                acc[nt][r] * invH;
}

// ---------------------------------------------------------------------------
extern "C" void kernel_launch(void* const* d_in, const int* in_sizes, int n_in,
                              void* d_out, int out_size, void* d_ws, size_t ws_size,
                              hipStream_t stream) {
    const float* x  = (const float*)d_in[0];
    const float* dr = (const float*)d_in[1];
    const float* Wq = (const float*)d_in[2];
    const float* bq = (const float*)d_in[3];
    const float* Wk = (const float*)d_in[4];
    const float* bk = (const float*)d_in[5];
    const float* Wv = (const float*)d_in[6];
    const float* bv = (const float*)d_in[7];
    const float* Wo = (const float*)d_in[8];
    const float* bo = (const float*)d_in[9];
    float* out = (float*)d_out;
    char* ws = (char*)d_ws;
    const size_t MB = 1ull << 20;

    bf16_t* xb   = (bf16_t*)(ws);             // 8 MB; reused as Vtmp
    bf16_t* xdb  = (bf16_t*)(ws + 8 * MB);    // 8 MB; reused as ctx
    bf16_t* Wqt  = (bf16_t*)(ws + 16 * MB);   // 2 MB each
    bf16_t* Wkt  = (bf16_t*)(ws + 18 * MB);
    bf16_t* Wvt  = (bf16_t*)(ws + 20 * MB);
    bf16_t* Wot  = (bf16_t*)(ws + 22 * MB);
    bf16_t* Qb   = (bf16_t*)(ws + 24 * MB);   // 8 MB
    bf16_t* Kb   = (bf16_t*)(ws + 32 * MB);   // 8 MB
    bf16_t* Vtb  = (bf16_t*)(ws + 40 * MB);   // 8 MB
    float*  logd = (float*)(ws + 48 * MB);    // 16 KB
    float*  mws  = (float*)(ws + 49 * MB);    // 256 KB
    float*  lws  = (float*)(ws + 50 * MB);    // 256 KB
    bf16_t* Vtmp = xb;    // dead after Q,K gemms
    bf16_t* ctx  = xdb;   // dead after V gemm

    prep_x_k<<<2048, 256, 0, stream>>>(x, dr, xb, xdb);
    dim3 gw(16, 16);
    prep_wt_k<<<gw, 256, 0, stream>>>(Wq, Wqt);
    prep_wt_k<<<gw, 256, 0, stream>>>(Wk, Wkt);
    prep_wt_k<<<gw, 256, 0, stream>>>(Wv, Wvt);
    prep_wt_k<<<gw, 256, 0, stream>>>(Wo, Wot);
    prep_logd_k<<<16, 256, 0, stream>>>(dr, logd);

    dim3 gg(16, 64);
    gemm_bf16_k<<<gg, 256, 0, stream>>>(xb,  Wqt, bq, nullptr, Qb,   0);
    gemm_bf16_k<<<gg, 256, 0, stream>>>(xb,  Wkt, bk, nullptr, Kb,   0);
    gemm_bf16_k<<<gg, 256, 0, stream>>>(xdb, Wvt, bv, nullptr, Vtmp, 0);

    vtrans_k<<<dim3(32, 32), 256, 0, stream>>>(Vtmp, Vtb);

    attn_flash_mfma_k<<<dim3(32, 32), 256, 0, stream>>>(Qb, Kb, Vtb, logd,
                                                        ctx, mws, lws);
    attn_mean_mfma_k<<<dim3(32, 32, 2), 256, 0, stream>>>(Qb, Kb, logd, mws, lws,
                                                          out + (size_t)MTOT * DMODEL);
    gemm_bf16_k<<<gg, 256, 0, stream>>>(ctx, Wot, bo, out, nullptr, 2);
}

// Round 3
// 339.957 us; speedup vs baseline: 10.0090x; 1.1523x over previous
//
#include <hip/hip_runtime.h>
#include <math.h>

#define DMODEL 1024
#define NHEAD  16
#define DK     64
#define BB     2
#define LL     2048
#define MTOT   (BB*LL)   // 4096

#define LOG2E      1.4426950408889634f
#define SCQ        (0.125f * LOG2E)    // folded into Q at projection epilogue
#define C2LOG      (0.1f * LOG2E)      // distance coeff in log2 domain

typedef __bf16 bf16_t;
typedef __bf16 bf16x8 __attribute__((ext_vector_type(8)));
typedef float  f32x4  __attribute__((ext_vector_type(4)));

static __device__ __forceinline__ f32x4 mfma16(bf16x8 a, bf16x8 b, f32x4 c) {
    return __builtin_amdgcn_mfma_f32_16x16x32_bf16(a, b, c, 0, 0, 0);
}
static __device__ __forceinline__ float exp2f_fast(float x) {
    return __builtin_amdgcn_exp2f(x);
}
static __device__ __forceinline__ float log2f_fast(float x) {
    return __builtin_amdgcn_logf(x);
}
// async global->LDS, 16B per lane. lds ptr must be wave-uniform; HW adds lane*16.
static __device__ __forceinline__ void gl_lds16(const bf16_t* g, bf16_t* l) {
    __builtin_amdgcn_global_load_lds(
        (const __attribute__((address_space(1))) unsigned int*)g,
        (__attribute__((address_space(3))) unsigned int*)l, 16, 0, 0);
}

// ---------------------------------------------------------------------------
// prep: x -> bf16; gid<MTOT also writes logd2 = log2(delta + 1e-6)
// ---------------------------------------------------------------------------
__global__ __launch_bounds__(256) void prep_x_k(
    const float* __restrict__ x, const float* __restrict__ dr,
    bf16_t* __restrict__ xb, float* __restrict__ logd2)
{
    size_t gid = (size_t)blockIdx.x * 256 + threadIdx.x;   // 524288 total
    size_t off = gid * 8;
    float4 a = *(const float4*)(x + off);
    float4 c = *(const float4*)(x + off + 4);
    float va[8] = {a.x, a.y, a.z, a.w, c.x, c.y, c.z, c.w};
    bf16x8 o1;
#pragma unroll
    for (int j = 0; j < 8; ++j) o1[j] = (bf16_t)va[j];
    *(bf16x8*)(xb + off) = o1;
    if (gid < MTOT) logd2[gid] = log2f_fast(dr[gid] + 1e-6f);
}

// ---------------------------------------------------------------------------
// prep: W[k][n] f32 -> Wt[n][k] bf16 (transpose + convert), 4 matrices by z.
// z=0..2 -> Wcat rows z*1024..; z=3 -> Wot
// ---------------------------------------------------------------------------
__global__ __launch_bounds__(256) void prep_w_k(
    const float* __restrict__ Wq, const float* __restrict__ Wk,
    const float* __restrict__ Wv, const float* __restrict__ Wo,
    bf16_t* __restrict__ Wcat, bf16_t* __restrict__ Wot)
{
    __shared__ __align__(16) float Ts[64][68];
    const int z = blockIdx.z;
    const float* W = (z == 0) ? Wq : (z == 1) ? Wk : (z == 2) ? Wv : Wo;
    bf16_t* dst = (z < 3) ? (Wcat + (size_t)z * DMODEL * DMODEL) : Wot;
    const int tid = threadIdx.x;
    const int k0 = blockIdx.x * 64, n0 = blockIdx.y * 64;
#pragma unroll
    for (int i = 0; i < 4; ++i) {
        int u = tid + 256 * i, r = u >> 4, c4 = (u & 15) * 4;
        *(float4*)&Ts[r][c4] = *(const float4*)(W + (size_t)(k0 + r) * DMODEL + n0 + c4);
    }
    __syncthreads();
#pragma unroll
    for (int i = 0; i < 2; ++i) {
        int u = tid + 256 * i, n = u >> 3, k8 = (u & 7) * 8;
        bf16x8 v;
#pragma unroll
        for (int j = 0; j < 8; ++j) v[j] = (bf16_t)Ts[k8 + j][n];
        *(bf16x8*)(dst + (size_t)(n0 + n) * DMODEL + k0 + k8) = v;
    }
}

// ---------------------------------------------------------------------------
// 128x128 MFMA GEMM, BK=64, global_load_lds + XOR-swizzled LDS.
// A [M,1024] bf16 row-major, Bt [N,1024] bf16 (k-major rows).
// mode 0 (N=3072): QKV epilogue -> Qb/Kb/Vtmp [b,h,l,dk] bf16
//   region Q: (acc+bq)*SCQ ; K: acc+bk ; V: acc*delta[m]+bv
// mode 1 (N=1024): outf[m][n] = acc + b0[n]  (f32)
// ---------------------------------------------------------------------------
__global__ __launch_bounds__(256, 3) void gemm128_k(
    const bf16_t* __restrict__ A, const bf16_t* __restrict__ Bt,
    const float* __restrict__ b0, const float* __restrict__ b1,
    const float* __restrict__ b2, const float* __restrict__ delta,
    float* __restrict__ outf, bf16_t* __restrict__ outQ,
    bf16_t* __restrict__ outK, bf16_t* __restrict__ outV, int mode)
{
    __shared__ __align__(16) bf16_t Asw[128 * 64];
    __shared__ __align__(16) bf16_t Bsw[128 * 64];
    const int tid = threadIdx.x, lane = tid & 63, w = tid >> 6;
    const int quad = lane >> 4, n16 = lane & 15;
    const int wm = (w & 1) * 64, wn = (w >> 1) * 64;
    const int m0 = blockIdx.y * 128, n0 = blockIdx.x * 128;
    const int srow = lane >> 3;              // 0..7
    const int scb  = (lane & 7) ^ srow;      // swizzled col block this lane fetches

    f32x4 acc[4][4] = {};

    for (int K0 = 0; K0 < DMODEL; K0 += 64) {
        __syncthreads();
#pragma unroll
        for (int i = 0; i < 4; ++i) {
            int rb = w * 32 + i * 8;         // wave-uniform row base
            gl_lds16(A  + (size_t)(m0 + rb + srow) * DMODEL + K0 + scb * 8,
                     &Asw[rb * 64]);
            gl_lds16(Bt + (size_t)(n0 + rb + srow) * DMODEL + K0 + scb * 8,
                     &Bsw[rb * 64]);
        }
        __syncthreads();
#pragma unroll
        for (int kc = 0; kc < 2; ++kc) {
            const int pcb = ((kc * 4 + quad) ^ (n16 & 7)) * 8;
            bf16x8 af[4], bfv[4];
#pragma unroll
            for (int mi = 0; mi < 4; ++mi)
                af[mi] = *(const bf16x8*)&Asw[(wm + mi * 16 + n16) * 64 + pcb];
#pragma unroll
            for (int ni = 0; ni < 4; ++ni)
                bfv[ni] = *(const bf16x8*)&Bsw[(wn + ni * 16 + n16) * 64 + pcb];
#pragma unroll
            for (int mi = 0; mi < 4; ++mi)
#pragma unroll
                for (int ni = 0; ni < 4; ++ni)
                    acc[mi][ni] = mfma16(af[mi], bfv[ni], acc[mi][ni]);
        }
    }

    if (mode == 0) {
        const int region = n0 >> 10;         // uniform per block (1024 % 128 == 0)
        const float* bias = (region == 0) ? b0 : (region == 1) ? b1 : b2;
        bf16_t* dst = (region == 0) ? outQ : (region == 1) ? outK : outV;
        const float qs = (region == 0) ? SCQ : 1.0f;
#pragma unroll
        for (int mi = 0; mi < 4; ++mi) {
#pragma unroll
            for (int r = 0; r < 4; ++r) {
                const int m = m0 + wm + mi * 16 + quad * 4 + r;
                const int bidx = m >> 11, l = m & (LL - 1);
                const float dm = (region == 2) ? delta[m] : 1.0f;
#pragma unroll
                for (int ni = 0; ni < 4; ++ni) {
                    const int nl = (n0 & 1023) + wn + ni * 16 + n16;
                    const int h = nl >> 6, dd = nl & 63;
                    float v = acc[mi][ni][r];
                    v = (region == 2) ? (v * dm + bias[nl]) : ((v + bias[nl]) * qs);
                    dst[(((size_t)(bidx * NHEAD + h) * LL) + l) * DK + dd] = (bf16_t)v;
                }
            }
        }
    } else {
#pragma unroll
        for (int mi = 0; mi < 4; ++mi) {
#pragma unroll
            for (int r = 0; r < 4; ++r) {
                const int m = m0 + wm + mi * 16 + quad * 4 + r;
#pragma unroll
                for (int ni = 0; ni < 4; ++ni) {
                    const int n = n0 + wn + ni * 16 + n16;
                    outf[(size_t)m * DMODEL + n] = acc[mi][ni][r] + b0[n];
                }
            }
        }
    }
}

// ---------------------------------------------------------------------------
// V[b,h,l,dk] bf16 -> Vt[b,h,dk,l] bf16
// ---------------------------------------------------------------------------
__global__ __launch_bounds__(256) void vtrans_k(
    const bf16_t* __restrict__ V, bf16_t* __restrict__ Vt)
{
    __shared__ __align__(16) bf16_t Ts[64][72];
    const int tid = threadIdx.x;
    const int bh = blockIdx.y;
    const int l0 = blockIdx.x * 64;
    const size_t base = (size_t)bh * LL * DK;
#pragma unroll
    for (int i = 0; i < 2; ++i) {
        int u = tid + 256 * i, r = u >> 3, c8 = (u & 7) * 8;
        *(bf16x8*)&Ts[r][c8] = *(const bf16x8*)(V + base + (size_t)(l0 + r) * DK + c8);
    }
    __syncthreads();
#pragma unroll
    for (int i = 0; i < 2; ++i) {
        int u = tid + 256 * i, dd = u >> 3, l8 = (u & 7) * 8;
        bf16x8 v;
#pragma unroll
        for (int j = 0; j < 8; ++j) v[j] = Ts[l8 + j][dd];
        *(bf16x8*)(Vt + base + (size_t)dd * LL + l0 + l8) = v;
    }
}

// ---------------------------------------------------------------------------
// MFMA flash attention (exp2 domain, Q pre-scaled by SCQ at projection):
// per block (b,h, 64 q rows). Writes ctx bf16 and stats (m2, l).
// ---------------------------------------------------------------------------
__global__ __launch_bounds__(256, 4) void attn_flash_mfma_k(
    const bf16_t* __restrict__ Q, const bf16_t* __restrict__ K,
    const bf16_t* __restrict__ Vt, const float* __restrict__ logd2,
    bf16_t* __restrict__ ctx, float* __restrict__ mout, float* __restrict__ lout)
{
    __shared__ __align__(16) bf16_t Ks[64][72];
    __shared__ __align__(16) bf16_t Vts[64][72];   // [d][key]
    __shared__ __align__(16) bf16_t Ps[4][16][72]; // per-wave P buffer
    __shared__ float logds[64];

    const int tid = threadIdx.x;
    const int lane = tid & 63, w = tid >> 6;
    const int quad = lane >> 4, n16 = lane & 15;
    const int bh = blockIdx.y, b = bh >> 4, h = bh & 15;
    const int q0 = blockIdx.x * 64;
    const size_t base = (size_t)bh * LL * DK;

    // Q fragments straight from global (each wave owns rows w*16 + n16)
    bf16x8 qa[2];
#pragma unroll
    for (int kc = 0; kc < 2; ++kc)
        qa[kc] = *(const bf16x8*)(Q + base + (size_t)(q0 + w * 16 + n16) * DK +
                                  kc * 32 + quad * 8);

    float m_r[4], l_r[4];
    f32x4 o[4] = {};
#pragma unroll
    for (int r = 0; r < 4; ++r) { m_r[r] = -1e30f; l_r[r] = 0.f; }

    const int qrow = q0 + w * 16 + quad * 4;   // + r

    for (int k0 = 0; k0 < LL; k0 += 64) {
        __syncthreads();
#pragma unroll
        for (int i = 0; i < 2; ++i) {
            int u = tid + 256 * i, r = u >> 3, c8 = (u & 7) * 8;
            *(bf16x8*)&Ks[r][c8]  = *(const bf16x8*)(K + base + (size_t)(k0 + r) * DK + c8);
            *(bf16x8*)&Vts[r][c8] = *(const bf16x8*)(Vt + base + (size_t)r * LL + k0 + c8);
        }
        if (tid < 64) logds[tid] = logd2[b * LL + k0 + tid];
        __syncthreads();

        // S = Q K^T (already in log2 scale via Q prescale)
        f32x4 s[4] = {};
#pragma unroll
        for (int kc = 0; kc < 2; ++kc) {
#pragma unroll
            for (int nt = 0; nt < 4; ++nt) {
                bf16x8 kb = *(const bf16x8*)&Ks[nt * 16 + n16][kc * 32 + quad * 8];
                s[nt] = mfma16(qa[kc], kb, s[nt]);
            }
        }
        // bias
        float sv[4][4];
#pragma unroll
        for (int nt = 0; nt < 4; ++nt) {
            const int kpos = k0 + nt * 16 + n16;
            const float basef = (float)(qrow - kpos);
            const float ld = logds[nt * 16 + n16];
#pragma unroll
            for (int r = 0; r < 4; ++r)
                sv[nt][r] = s[nt][r] + fmaf(fabsf(basef + (float)r), -C2LOG, ld);
        }
        // online softmax per row (log2 domain)
#pragma unroll
        for (int r = 0; r < 4; ++r) {
            float rm = fmaxf(fmaxf(sv[0][r], sv[1][r]), fmaxf(sv[2][r], sv[3][r]));
#pragma unroll
            for (int off = 8; off >= 1; off >>= 1)
                rm = fmaxf(rm, __shfl_xor(rm, off));
            const float mn = fmaxf(m_r[r], rm);
            const float alpha = exp2f_fast(m_r[r] - mn);
            float psum = 0.f;
#pragma unroll
            for (int nt = 0; nt < 4; ++nt) {
                float p = exp2f_fast(sv[nt][r] - mn);
                sv[nt][r] = p;
                psum += p;
            }
#pragma unroll
            for (int off = 8; off >= 1; off >>= 1)
                psum += __shfl_xor(psum, off);
            l_r[r] = l_r[r] * alpha + psum;
            m_r[r] = mn;
#pragma unroll
            for (int dt = 0; dt < 4; ++dt) o[dt][r] *= alpha;
        }
        // P: C-layout -> A-layout via wave-private LDS
#pragma unroll
        for (int nt = 0; nt < 4; ++nt)
#pragma unroll
            for (int r = 0; r < 4; ++r)
                Ps[w][quad * 4 + r][nt * 16 + n16] = (bf16_t)sv[nt][r];
        __threadfence_block();
        // O += P V
#pragma unroll
        for (int kc = 0; kc < 2; ++kc) {
            bf16x8 pa = *(const bf16x8*)&Ps[w][n16][kc * 32 + quad * 8];
#pragma unroll
            for (int dt = 0; dt < 4; ++dt) {
                bf16x8 vb = *(const bf16x8*)&Vts[dt * 16 + n16][kc * 32 + quad * 8];
                o[dt] = mfma16(pa, vb, o[dt]);
            }
        }
    }
    // epilogue
#pragma unroll
    for (int r = 0; r < 4; ++r) {
        const float inv = 1.f / l_r[r];
        const int q = qrow + r;
#pragma unroll
        for (int dt = 0; dt < 4; ++dt)
            ctx[((size_t)(b * LL) + q) * DMODEL + h * DK + dt * 16 + n16] =
                (bf16_t)(o[dt][r] * inv);
    }
    if (n16 == 0) {
#pragma unroll
        for (int r = 0; r < 4; ++r) {
            mout[(size_t)bh * LL + qrow + r] = m_r[r];
            lout[(size_t)bh * LL + qrow + r] = l_r[r];
        }
    }
}

// ---------------------------------------------------------------------------
// attn.mean(heads): per block (b, 64 q, 64 k); double-buffered K staging with
// register prefetch; Q-frags from global; normalization folded into exponent.
// ---------------------------------------------------------------------------
__global__ __launch_bounds__(256, 4) void attn_mean_mfma_k(
    const bf16_t* __restrict__ Q, const bf16_t* __restrict__ K,
    const float* __restrict__ logd2, const float* __restrict__ mws,
    const float* __restrict__ lws, float* __restrict__ outmean)
{
    __shared__ __align__(16) bf16_t Ks[2][64][72];
    __shared__ float mls[2][64];
    __shared__ float logds[64];

    const int tid = threadIdx.x;
    const int lane = tid & 63, w = tid >> 6;
    const int quad = lane >> 4, n16 = lane & 15;
    const int k0 = blockIdx.x * 64, q0 = blockIdx.y * 64, b = blockIdx.z;

    if (tid < 64) logds[tid] = logd2[b * LL + k0 + tid];

    const int qrow = q0 + w * 16 + quad * 4;
    const int sr = tid >> 3, sc8 = (tid & 7) * 8;       // K staging row/col (i=0)
    const int sr2 = (tid + 256) >> 3;                   // (i=1)

    f32x4 acc[4] = {};

    // prefetch registers for head h+? loads
    bf16x8 kr0, kr1, qan[2];
    float mlv = 0.f;

    auto load_head = [&](int h) {
        const size_t hb = (size_t)(b * NHEAD + h) * LL * DK;
        kr0 = *(const bf16x8*)(K + hb + (size_t)(k0 + sr)  * DK + sc8);
        kr1 = *(const bf16x8*)(K + hb + (size_t)(k0 + sr2) * DK + sc8);
#pragma unroll
        for (int kc = 0; kc < 2; ++kc)
            qan[kc] = *(const bf16x8*)(Q + hb + (size_t)(q0 + w * 16 + n16) * DK +
                                       kc * 32 + quad * 8);
        if (tid < 64) {
            const size_t si = (size_t)(b * NHEAD + h) * LL + q0 + tid;
            mlv = mws[si] + log2f_fast(lws[si]);
        }
    };

    load_head(0);
    for (int h = 0; h < NHEAD; ++h) {
        const int p = h & 1;
        // write phase
        *(bf16x8*)&Ks[p][sr][sc8]  = kr0;
        *(bf16x8*)&Ks[p][sr2][sc8] = kr1;
        if (tid < 64) mls[p][tid] = mlv;
        bf16x8 qc[2] = {qan[0], qan[1]};
        __syncthreads();
        if (h + 1 < NHEAD) load_head(h + 1);

        f32x4 s[4] = {};
#pragma unroll
        for (int kc = 0; kc < 2; ++kc) {
#pragma unroll
            for (int nt = 0; nt < 4; ++nt) {
                bf16x8 kb = *(const bf16x8*)&Ks[p][nt * 16 + n16][kc * 32 + quad * 8];
                s[nt] = mfma16(qc[kc], kb, s[nt]);
            }
        }
#pragma unroll
        for (int nt = 0; nt < 4; ++nt) {
            const int kpos = k0 + nt * 16 + n16;
            const float basef = (float)(qrow - kpos);
            const float ld = logds[nt * 16 + n16];
#pragma unroll
            for (int r = 0; r < 4; ++r) {
                const float svv = s[nt][r] + fmaf(fabsf(basef + (float)r), -C2LOG, ld);
                acc[nt][r] += exp2f_fast(svv - mls[p][w * 16 + quad * 4 + r]);
            }
        }
        // dbuf: next head writes the other buffer; one barrier per iter is enough
    }
    const float invH = 1.f / (float)NHEAD;
#pragma unroll
    for (int nt = 0; nt < 4; ++nt)
#pragma unroll
        for (int r = 0; r < 4; ++r)
            outmean[((size_t)b * LL + qrow + r) * LL + k0 + nt * 16 + n16] =
                acc[nt][r] * invH;
}

// ---------------------------------------------------------------------------
extern "C" void kernel_launch(void* const* d_in, const int* in_sizes, int n_in,
                              void* d_out, int out_size, void* d_ws, size_t ws_size,
                              hipStream_t stream) {
    const float* x  = (const float*)d_in[0];
    const float* dr = (const float*)d_in[1];
    const float* Wq = (const float*)d_in[2];
    const float* bq = (const float*)d_in[3];
    const float* Wk = (const float*)d_in[4];
    const float* bk = (const float*)d_in[5];
    const float* Wv = (const float*)d_in[6];
    const float* bv = (const float*)d_in[7];
    const float* Wo = (const float*)d_in[8];
    const float* bo = (const float*)d_in[9];
    float* out = (float*)d_out;
    char* ws = (char*)d_ws;
    const size_t MB = 1ull << 20;

    bf16_t* xb   = (bf16_t*)(ws);             // 8 MB; reused as Vtb after QKV gemm
    bf16_t* Wcat = (bf16_t*)(ws + 8 * MB);    // 6 MB  [3072][1024]
    bf16_t* Wot  = (bf16_t*)(ws + 14 * MB);   // 2 MB
    bf16_t* Qb   = (bf16_t*)(ws + 16 * MB);   // 8 MB
    bf16_t* Kb   = (bf16_t*)(ws + 24 * MB);   // 8 MB
    bf16_t* Vtmp = (bf16_t*)(ws + 32 * MB);   // 8 MB; reused as ctx after vtrans
    float*  logd = (float*)(ws + 40 * MB);    // 16 KB
    float*  mws  = (float*)(ws + 41 * MB);    // 256 KB
    float*  lws  = (float*)(ws + 42 * MB);    // 256 KB
    bf16_t* Vtb  = xb;
    bf16_t* ctx  = Vtmp;

    prep_x_k<<<2048, 256, 0, stream>>>(x, dr, xb, logd);
    prep_w_k<<<dim3(16, 16, 4), 256, 0, stream>>>(Wq, Wk, Wv, Wo, Wcat, Wot);

    // fused QKV projection: N = 3072
    gemm128_k<<<dim3(24, 32), 256, 0, stream>>>(xb, Wcat, bq, bk, bv, dr,
                                                nullptr, Qb, Kb, Vtmp, 0);
    vtrans_k<<<dim3(32, 32), 256, 0, stream>>>(Vtmp, Vtb);

    attn_flash_mfma_k<<<dim3(32, 32), 256, 0, stream>>>(Qb, Kb, Vtb, logd,
                                                        ctx, mws, lws);
    attn_mean_mfma_k<<<dim3(32, 32, 2), 256, 0, stream>>>(Qb, Kb, logd, mws, lws,
                                                          out + (size_t)MTOT * DMODEL);
    // output projection
    gemm128_k<<<dim3(8, 32), 256, 0, stream>>>(ctx, Wot, bo, nullptr, nullptr,
                                               nullptr, out, nullptr, nullptr,
                                               nullptr, 1);
}

// Round 4
// 280.653 us; speedup vs baseline: 12.1240x; 1.2113x over previous
//
#include <hip/hip_runtime.h>
#include <math.h>

#define DMODEL 1024
#define NHEAD  16
#define DK     64
#define BB     2
#define LL     2048
#define MTOT   (BB*LL)   // 4096

#define LOG2E      1.4426950408889634f
#define SCQ        (0.125f * LOG2E)    // folded into Q at projection epilogue
#define C2LOG      (0.1f * LOG2E)      // distance coeff in log2 domain

typedef __bf16 bf16_t;
typedef __bf16 bf16x8 __attribute__((ext_vector_type(8)));
typedef __bf16 bf16x4 __attribute__((ext_vector_type(4)));
typedef float  f32x4  __attribute__((ext_vector_type(4)));

static __device__ __forceinline__ f32x4 mfma16(bf16x8 a, bf16x8 b, f32x4 c) {
    return __builtin_amdgcn_mfma_f32_16x16x32_bf16(a, b, c, 0, 0, 0);
}
static __device__ __forceinline__ float exp2f_fast(float x) {
    return __builtin_amdgcn_exp2f(x);
}
static __device__ __forceinline__ float log2f_fast(float x) {
    return __builtin_amdgcn_logf(x);
}
// async global->LDS, 16B per lane. lds ptr must be wave-uniform; HW adds lane*16.
static __device__ __forceinline__ void gl_lds16(const bf16_t* g, bf16_t* l) {
    __builtin_amdgcn_global_load_lds(
        (const __attribute__((address_space(1))) unsigned int*)g,
        (__attribute__((address_space(3))) unsigned int*)l, 16, 0, 0);
}

// ---------------------------------------------------------------------------
// prep: x -> bf16; gid<MTOT also writes logd2 = log2(delta + 1e-6)
// ---------------------------------------------------------------------------
__global__ __launch_bounds__(256) void prep_x_k(
    const float* __restrict__ x, const float* __restrict__ dr,
    bf16_t* __restrict__ xb, float* __restrict__ logd2)
{
    size_t gid = (size_t)blockIdx.x * 256 + threadIdx.x;   // 524288 total
    size_t off = gid * 8;
    float4 a = *(const float4*)(x + off);
    float4 c = *(const float4*)(x + off + 4);
    float va[8] = {a.x, a.y, a.z, a.w, c.x, c.y, c.z, c.w};
    bf16x8 o1;
#pragma unroll
    for (int j = 0; j < 8; ++j) o1[j] = (bf16_t)va[j];
    *(bf16x8*)(xb + off) = o1;
    if (gid < MTOT) logd2[gid] = log2f_fast(dr[gid] + 1e-6f);
}

// ---------------------------------------------------------------------------
// prep: W[k][n] f32 -> Wt[n][k] bf16 (transpose + convert), 4 matrices by z.
// ---------------------------------------------------------------------------
__global__ __launch_bounds__(256) void prep_w_k(
    const float* __restrict__ Wq, const float* __restrict__ Wk,
    const float* __restrict__ Wv, const float* __restrict__ Wo,
    bf16_t* __restrict__ Wcat, bf16_t* __restrict__ Wot)
{
    __shared__ __align__(16) float Ts[64][68];
    const int z = blockIdx.z;
    const float* W = (z == 0) ? Wq : (z == 1) ? Wk : (z == 2) ? Wv : Wo;
    bf16_t* dst = (z < 3) ? (Wcat + (size_t)z * DMODEL * DMODEL) : Wot;
    const int tid = threadIdx.x;
    const int k0 = blockIdx.x * 64, n0 = blockIdx.y * 64;
#pragma unroll
    for (int i = 0; i < 4; ++i) {
        int u = tid + 256 * i, r = u >> 4, c4 = (u & 15) * 4;
        *(float4*)&Ts[r][c4] = *(const float4*)(W + (size_t)(k0 + r) * DMODEL + n0 + c4);
    }
    __syncthreads();
#pragma unroll
    for (int i = 0; i < 2; ++i) {
        int u = tid + 256 * i, n = u >> 3, k8 = (u & 7) * 8;
        bf16x8 v;
#pragma unroll
        for (int j = 0; j < 8; ++j) v[j] = (bf16_t)Ts[k8 + j][n];
        *(bf16x8*)(dst + (size_t)(n0 + n) * DMODEL + k0 + k8) = v;
    }
}

// ---------------------------------------------------------------------------
// 128x128 MFMA GEMM, BK=64, global_load_lds + XOR-swizzled LDS.
// mode 0 (N=3072): QKV epilogue -> Qb/Kb/Vtmp [b,h,l,dk] bf16
// mode 1 (N=1024): outf[m][n] = acc + b0[n]  (f32)
// ---------------------------------------------------------------------------
__global__ __launch_bounds__(256, 3) void gemm128_k(
    const bf16_t* __restrict__ A, const bf16_t* __restrict__ Bt,
    const float* __restrict__ b0, const float* __restrict__ b1,
    const float* __restrict__ b2, const float* __restrict__ delta,
    float* __restrict__ outf, bf16_t* __restrict__ outQ,
    bf16_t* __restrict__ outK, bf16_t* __restrict__ outV, int mode)
{
    __shared__ __align__(16) bf16_t Asw[128 * 64];
    __shared__ __align__(16) bf16_t Bsw[128 * 64];
    const int tid = threadIdx.x, lane = tid & 63, w = tid >> 6;
    const int quad = lane >> 4, n16 = lane & 15;
    const int wm = (w & 1) * 64, wn = (w >> 1) * 64;
    const int m0 = blockIdx.y * 128, n0 = blockIdx.x * 128;
    const int srow = lane >> 3;              // 0..7
    const int scb  = (lane & 7) ^ srow;      // swizzled col block this lane fetches

    f32x4 acc[4][4] = {};

    for (int K0 = 0; K0 < DMODEL; K0 += 64) {
        __syncthreads();
#pragma unroll
        for (int i = 0; i < 4; ++i) {
            int rb = w * 32 + i * 8;         // wave-uniform row base
            gl_lds16(A  + (size_t)(m0 + rb + srow) * DMODEL + K0 + scb * 8,
                     &Asw[rb * 64]);
            gl_lds16(Bt + (size_t)(n0 + rb + srow) * DMODEL + K0 + scb * 8,
                     &Bsw[rb * 64]);
        }
        __syncthreads();
#pragma unroll
        for (int kc = 0; kc < 2; ++kc) {
            const int pcb = ((kc * 4 + quad) ^ (n16 & 7)) * 8;
            bf16x8 af[4], bfv[4];
#pragma unroll
            for (int mi = 0; mi < 4; ++mi)
                af[mi] = *(const bf16x8*)&Asw[(wm + mi * 16 + n16) * 64 + pcb];
#pragma unroll
            for (int ni = 0; ni < 4; ++ni)
                bfv[ni] = *(const bf16x8*)&Bsw[(wn + ni * 16 + n16) * 64 + pcb];
#pragma unroll
            for (int mi = 0; mi < 4; ++mi)
#pragma unroll
                for (int ni = 0; ni < 4; ++ni)
                    acc[mi][ni] = mfma16(af[mi], bfv[ni], acc[mi][ni]);
        }
    }

    if (mode == 0) {
        const int region = n0 >> 10;         // uniform per block
        const float* bias = (region == 0) ? b0 : (region == 1) ? b1 : b2;
        bf16_t* dst = (region == 0) ? outQ : (region == 1) ? outK : outV;
        const float qs = (region == 0) ? SCQ : 1.0f;
#pragma unroll
        for (int mi = 0; mi < 4; ++mi) {
#pragma unroll
            for (int r = 0; r < 4; ++r) {
                const int m = m0 + wm + mi * 16 + quad * 4 + r;
                const int bidx = m >> 11, l = m & (LL - 1);
                const float dm = (region == 2) ? delta[m] : 1.0f;
#pragma unroll
                for (int ni = 0; ni < 4; ++ni) {
                    const int nl = (n0 & 1023) + wn + ni * 16 + n16;
                    const int h = nl >> 6, dd = nl & 63;
                    float v = acc[mi][ni][r];
                    v = (region == 2) ? (v * dm + bias[nl]) : ((v + bias[nl]) * qs);
                    dst[(((size_t)(bidx * NHEAD + h) * LL) + l) * DK + dd] = (bf16_t)v;
                }
            }
        }
    } else {
#pragma unroll
        for (int mi = 0; mi < 4; ++mi) {
#pragma unroll
            for (int r = 0; r < 4; ++r) {
                const int m = m0 + wm + mi * 16 + quad * 4 + r;
#pragma unroll
                for (int ni = 0; ni < 4; ++ni) {
                    const int n = n0 + wn + ni * 16 + n16;
                    outf[(size_t)m * DMODEL + n] = acc[mi][ni][r] + b0[n];
                }
            }
        }
    }
}

// ---------------------------------------------------------------------------
// V[b,h,l,dk] bf16 -> Vt[b,h,dk,l] bf16
// ---------------------------------------------------------------------------
__global__ __launch_bounds__(256) void vtrans_k(
    const bf16_t* __restrict__ V, bf16_t* __restrict__ Vt)
{
    __shared__ __align__(16) bf16_t Ts[64][72];
    const int tid = threadIdx.x;
    const int bh = blockIdx.y;
    const int l0 = blockIdx.x * 64;
    const size_t base = (size_t)bh * LL * DK;
#pragma unroll
    for (int i = 0; i < 2; ++i) {
        int u = tid + 256 * i, r = u >> 3, c8 = (u & 7) * 8;
        *(bf16x8*)&Ts[r][c8] = *(const bf16x8*)(V + base + (size_t)(l0 + r) * DK + c8);
    }
    __syncthreads();
#pragma unroll
    for (int i = 0; i < 2; ++i) {
        int u = tid + 256 * i, dd = u >> 3, l8 = (u & 7) * 8;
        bf16x8 v;
#pragma unroll
        for (int j = 0; j < 8; ++j) v[j] = Ts[l8 + j][dd];
        *(bf16x8*)(Vt + base + (size_t)dd * LL + l0 + l8) = v;
    }
}

// ---------------------------------------------------------------------------
// MFMA flash attention, S^T formulation (exp2 domain):
// per block (b,h, 64 q). Each lane owns ONE q-column: softmax state scalar.
// S^T = K·Q^T (A=K-frag, B=Q-frag); PV as O^T = V^T·P^T (A=Vt, B=P^T).
// Register-prefetch staging: global latency hidden behind tile compute.
// Writes ctx bf16 and ml = m + log2(l).
// ---------------------------------------------------------------------------
__global__ __launch_bounds__(256, 4) void attn_flash_mfma_k(
    const bf16_t* __restrict__ Q, const bf16_t* __restrict__ K,
    const bf16_t* __restrict__ Vt, const float* __restrict__ logd2,
    bf16_t* __restrict__ ctx, float* __restrict__ mlout)
{
    __shared__ __align__(16) bf16_t Ks[64][72];
    __shared__ __align__(16) bf16_t Vts[64][72];   // [d][key]
    __shared__ __align__(16) bf16_t Ps[4][16][72]; // per-wave P, [q][k]
    __shared__ float logds[64];

    const int tid = threadIdx.x;
    const int lane = tid & 63, w = tid >> 6;
    const int quad = lane >> 4, n16 = lane & 15;
    const int bh = blockIdx.y, b = bh >> 4, h = bh & 15;
    const int q0 = blockIdx.x * 64;
    const size_t base = (size_t)bh * LL * DK;
    const int q = q0 + w * 16 + n16;               // this lane's q column

    // Q B-frags straight from global, kept for the whole kernel
    bf16x8 qa[2];
#pragma unroll
    for (int kc = 0; kc < 2; ++kc)
        qa[kc] = *(const bf16x8*)(Q + base + (size_t)q * DK + kc * 32 + quad * 8);

    const int strow = tid >> 3, stc8 = (tid & 7) * 8;   // staging row/col

    bf16x8 kr0, kr1, vr0, vr1;
    float ldr = 0.f;
    auto prefetch = [&](int k0) {
        kr0 = *(const bf16x8*)(K + base + (size_t)(k0 + strow) * DK + stc8);
        kr1 = *(const bf16x8*)(K + base + (size_t)(k0 + 32 + strow) * DK + stc8);
        vr0 = *(const bf16x8*)(Vt + base + (size_t)strow * LL + k0 + stc8);
        vr1 = *(const bf16x8*)(Vt + base + (size_t)(32 + strow) * LL + k0 + stc8);
        if (tid < 64) ldr = logd2[b * LL + k0 + tid];
    };

    float m_c = -1e30f, l_c = 0.f;
    f32x4 o[4] = {};
    const float dfq = (float)(q - quad * 4);

    prefetch(0);
    for (int k0 = 0; k0 < LL; k0 += 64) {
        __syncthreads();
        *(bf16x8*)&Ks[strow][stc8]       = kr0;
        *(bf16x8*)&Ks[32 + strow][stc8]  = kr1;
        *(bf16x8*)&Vts[strow][stc8]      = vr0;
        *(bf16x8*)&Vts[32 + strow][stc8] = vr1;
        if (tid < 64) logds[tid] = ldr;
        __syncthreads();
        if (k0 + 64 < LL) prefetch(k0 + 64);

        // S^T tiles: s[kt][r] = S[q][k0 + kt*16 + quad*4 + r]
        f32x4 s[4] = {};
#pragma unroll
        for (int kc = 0; kc < 2; ++kc) {
#pragma unroll
            for (int kt = 0; kt < 4; ++kt) {
                bf16x8 kb = *(const bf16x8*)&Ks[kt * 16 + n16][kc * 32 + quad * 8];
                s[kt] = mfma16(kb, qa[kc], s[kt]);
            }
        }
        // bias (log2 domain)
        const float df = dfq - (float)k0;
#pragma unroll
        for (int kt = 0; kt < 4; ++kt) {
            f32x4 ldv = *(const f32x4*)&logds[kt * 16 + quad * 4];
#pragma unroll
            for (int r = 0; r < 4; ++r)
                s[kt][r] += ldv[r] - C2LOG * fabsf(df - (float)(kt * 16 + r));
        }
        // per-lane online softmax (16 values in-register + 2 shfls)
        f32x4 mx;
#pragma unroll
        for (int r = 0; r < 4; ++r)
            mx[r] = fmaxf(fmaxf(s[0][r], s[1][r]), fmaxf(s[2][r], s[3][r]));
        float rm = fmaxf(fmaxf(mx[0], mx[1]), fmaxf(mx[2], mx[3]));
        rm = fmaxf(rm, __shfl_xor(rm, 16));
        rm = fmaxf(rm, __shfl_xor(rm, 32));
        const float mn = fmaxf(m_c, rm);
        const float alpha = exp2f_fast(m_c - mn);
        f32x4 ps = {0.f, 0.f, 0.f, 0.f};
#pragma unroll
        for (int kt = 0; kt < 4; ++kt)
#pragma unroll
            for (int r = 0; r < 4; ++r) {
                float p = exp2f_fast(s[kt][r] - mn);
                s[kt][r] = p;
                ps[r] += p;
            }
        float psum = (ps[0] + ps[1]) + (ps[2] + ps[3]);
        psum += __shfl_xor(psum, 16);
        psum += __shfl_xor(psum, 32);
        l_c = l_c * alpha + psum;
        m_c = mn;
#pragma unroll
        for (int dt = 0; dt < 4; ++dt)
#pragma unroll
            for (int r = 0; r < 4; ++r) o[dt][r] *= alpha;
        // P pack: 4 consecutive k per kt -> b64 writes into [q][k] layout
#pragma unroll
        for (int kt = 0; kt < 4; ++kt) {
            bf16x4 pk;
#pragma unroll
            for (int r = 0; r < 4; ++r) pk[r] = (bf16_t)s[kt][r];
            *(bf16x4*)&Ps[w][n16][kt * 16 + quad * 4] = pk;
        }
        __threadfence_block();
        // O^T += V^T P^T
#pragma unroll
        for (int kc = 0; kc < 2; ++kc) {
            bf16x8 pa = *(const bf16x8*)&Ps[w][n16][kc * 32 + quad * 8];
#pragma unroll
            for (int dt = 0; dt < 4; ++dt) {
                bf16x8 vb = *(const bf16x8*)&Vts[dt * 16 + n16][kc * 32 + quad * 8];
                o[dt] = mfma16(vb, pa, o[dt]);
            }
        }
    }
    // epilogue: lane owns q-column; d = dt*16 + quad*4 + r -> packed b64 stores
    const float inv = 1.f / l_c;
#pragma unroll
    for (int dt = 0; dt < 4; ++dt) {
        bf16x4 ov;
#pragma unroll
        for (int r = 0; r < 4; ++r) ov[r] = (bf16_t)(o[dt][r] * inv);
        *(bf16x4*)(ctx + ((size_t)b * LL + q) * DMODEL + h * DK + dt * 16 + quad * 4) = ov;
    }
    if (quad == 0)
        mlout[(size_t)bh * LL + q] = m_c + log2f_fast(l_c);
}

// ---------------------------------------------------------------------------
// attn.mean(heads), S^T formulation: per block (b, 64 q, 64 k); loop heads,
// recompute S^T with identical MFMA sequence, normalize via stored ml.
// K staged double-buffered with register prefetch (1 barrier/iter).
// ---------------------------------------------------------------------------
__global__ __launch_bounds__(256, 4) void attn_mean_mfma_k(
    const bf16_t* __restrict__ Q, const bf16_t* __restrict__ K,
    const float* __restrict__ logd2, const float* __restrict__ mlws,
    float* __restrict__ outmean)
{
    __shared__ __align__(16) bf16_t Ks[2][64][72];
    __shared__ float mls[2][64];
    __shared__ float logds[64];

    const int tid = threadIdx.x;
    const int lane = tid & 63, w = tid >> 6;
    const int quad = lane >> 4, n16 = lane & 15;
    const int k0 = blockIdx.x * 64, q0 = blockIdx.y * 64, b = blockIdx.z;
    const int q = q0 + w * 16 + n16;

    if (tid < 64) logds[tid] = logd2[b * LL + k0 + tid];

    const int strow = tid >> 3, stc8 = (tid & 7) * 8;

    bf16x8 kr0, kr1, qan[2];
    float mlv = 0.f;
    auto load_head = [&](int h) {
        const size_t hb = (size_t)(b * NHEAD + h) * LL * DK;
        kr0 = *(const bf16x8*)(K + hb + (size_t)(k0 + strow) * DK + stc8);
        kr1 = *(const bf16x8*)(K + hb + (size_t)(k0 + 32 + strow) * DK + stc8);
#pragma unroll
        for (int kc = 0; kc < 2; ++kc)
            qan[kc] = *(const bf16x8*)(Q + hb + (size_t)q * DK + kc * 32 + quad * 8);
        if (tid < 64) mlv = mlws[(size_t)(b * NHEAD + h) * LL + q0 + tid];
    };

    f32x4 acc[4] = {};
    const float dfq = (float)(q - k0 - quad * 4);

    load_head(0);
    for (int h = 0; h < NHEAD; ++h) {
        const int p = h & 1;
        *(bf16x8*)&Ks[p][strow][stc8]      = kr0;
        *(bf16x8*)&Ks[p][32 + strow][stc8] = kr1;
        if (tid < 64) mls[p][tid] = mlv;
        bf16x8 qc[2] = {qan[0], qan[1]};
        __syncthreads();
        if (h + 1 < NHEAD) load_head(h + 1);

        f32x4 s[4] = {};
#pragma unroll
        for (int kc = 0; kc < 2; ++kc) {
#pragma unroll
            for (int kt = 0; kt < 4; ++kt) {
                bf16x8 kb = *(const bf16x8*)&Ks[p][kt * 16 + n16][kc * 32 + quad * 8];
                s[kt] = mfma16(kb, qc[kc], s[kt]);
            }
        }
        const float ml = mls[p][w * 16 + n16];
#pragma unroll
        for (int kt = 0; kt < 4; ++kt) {
            f32x4 ldv = *(const f32x4*)&logds[kt * 16 + quad * 4];
#pragma unroll
            for (int r = 0; r < 4; ++r) {
                const float arg = s[kt][r] + ldv[r]
                                - C2LOG * fabsf(dfq - (float)(kt * 16 + r)) - ml;
                acc[kt][r] += exp2f_fast(arg);
            }
        }
    }
    const float invH = 1.f / (float)NHEAD;
#pragma unroll
    for (int kt = 0; kt < 4; ++kt) {
        f32x4 ov;
#pragma unroll
        for (int r = 0; r < 4; ++r) ov[r] = acc[kt][r] * invH;
        *(f32x4*)(outmean + ((size_t)b * LL + q) * LL + k0 + kt * 16 + quad * 4) = ov;
    }
}

// ---------------------------------------------------------------------------
extern "C" void kernel_launch(void* const* d_in, const int* in_sizes, int n_in,
                              void* d_out, int out_size, void* d_ws, size_t ws_size,
                              hipStream_t stream) {
    const float* x  = (const float*)d_in[0];
    const float* dr = (const float*)d_in[1];
    const float* Wq = (const float*)d_in[2];
    const float* bq = (const float*)d_in[3];
    const float* Wk = (const float*)d_in[4];
    const float* bk = (const float*)d_in[5];
    const float* Wv = (const float*)d_in[6];
    const float* bv = (const float*)d_in[7];
    const float* Wo = (const float*)d_in[8];
    const float* bo = (const float*)d_in[9];
    float* out = (float*)d_out;
    char* ws = (char*)d_ws;
    const size_t MB = 1ull << 20;

    bf16_t* xb   = (bf16_t*)(ws);             // 8 MB; reused as Vtb after QKV gemm
    bf16_t* Wcat = (bf16_t*)(ws + 8 * MB);    // 6 MB  [3072][1024]
    bf16_t* Wot  = (bf16_t*)(ws + 14 * MB);   // 2 MB
    bf16_t* Qb   = (bf16_t*)(ws + 16 * MB);   // 8 MB
    bf16_t* Kb   = (bf16_t*)(ws + 24 * MB);   // 8 MB
    bf16_t* Vtmp = (bf16_t*)(ws + 32 * MB);   // 8 MB; reused as ctx after vtrans
    float*  logd = (float*)(ws + 40 * MB);    // 16 KB
    float*  mlws = (float*)(ws + 41 * MB);    // 256 KB
    bf16_t* Vtb  = xb;
    bf16_t* ctx  = Vtmp;

    prep_x_k<<<2048, 256, 0, stream>>>(x, dr, xb, logd);
    prep_w_k<<<dim3(16, 16, 4), 256, 0, stream>>>(Wq, Wk, Wv, Wo, Wcat, Wot);

    // fused QKV projection: N = 3072
    gemm128_k<<<dim3(24, 32), 256, 0, stream>>>(xb, Wcat, bq, bk, bv, dr,
                                                nullptr, Qb, Kb, Vtmp, 0);
    vtrans_k<<<dim3(32, 32), 256, 0, stream>>>(Vtmp, Vtb);

    attn_flash_mfma_k<<<dim3(32, 32), 256, 0, stream>>>(Qb, Kb, Vtb, logd,
                                                        ctx, mlws);
    attn_mean_mfma_k<<<dim3(32, 32, 2), 256, 0, stream>>>(Qb, Kb, logd, mlws,
                                                          out + (size_t)MTOT * DMODEL);
    // output projection
    gemm128_k<<<dim3(8, 32), 256, 0, stream>>>(ctx, Wot, bo, nullptr, nullptr,
                                               nullptr, out, nullptr, nullptr,
                                               nullptr, 1);
}